// Round 8
// baseline (212.420 us; speedup 1.0000x reference)
//
#include <hip/hip_runtime.h>

namespace {

typedef float v2f __attribute__((ext_vector_type(2)));
typedef float v4f __attribute__((ext_vector_type(4)));

constexpr int kB = 4, kCin = 4, kCout = 4;
constexpr int kD1 = 32, kD2 = 32, kH = 64, kW = 64;
constexpr int kHO = 32, kWO = 32;
constexpr int kSlice = kH * kW;                       // 4096
constexpr size_t kCiStride = (size_t)kD1 * kD2 * kSlice;

__device__ __forceinline__ void do_load(const float* __restrict__ sp0,
                                        v4f (&r0)[4], v4f (&r1)[4]) {
    #pragma unroll
    for (int ci = 0; ci < kCin; ++ci) {
        const float* sp = sp0 + (size_t)ci * kCiStride;
        r0[ci] = *reinterpret_cast<const v4f*>(sp);
        r1[ci] = *reinterpret_cast<const v4f*>(sp + kW);
    }
}

template <int E1, int E2>
__device__ __forceinline__ void do_fma(const v4f (&r0)[4], const v4f (&r1)[4],
                                       const float* __restrict__ w,
                                       v2f (&acc)[2][2][kCout][2]) {
    #pragma unroll
    for (int ci = 0; ci < kCin; ++ci) {
        const v2f xa0 = r0[ci].xy, xa1 = r0[ci].zw;
        const v2f xb0 = r1[ci].xy, xb1 = r1[ci].zw;
        #pragma unroll
        for (int uu = 0; uu < 2; ++uu) {
            constexpr int e1 = E1;
            const int ku = e1 - uu;
            if (ku < 0 || ku > 2) continue;          // compile-time
            #pragma unroll
            for (int vv = 0; vv < 2; ++vv) {
                constexpr int e2 = E2;
                const int kv = e2 - vv;
                if (kv < 0 || kv > 2) continue;      // compile-time
                #pragma unroll
                for (int co = 0; co < kCout; ++co) {
                    // Fully-constant index -> uniform s_load_dwordx4.
                    const v4f wv = *reinterpret_cast<const v4f*>(
                        w + (((co * kCin + ci) * 3 + ku) * 3 + kv) * 4);
                    const v2f w01 = wv.xy, w23 = wv.zw;
                    acc[uu][vv][co][0] =
                        __builtin_elementwise_fma(xa0, w01, acc[uu][vv][co][0]);
                    acc[uu][vv][co][0] =
                        __builtin_elementwise_fma(xb0, w23, acc[uu][vv][co][0]);
                    acc[uu][vv][co][1] =
                        __builtin_elementwise_fma(xa1, w01, acc[uu][vv][co][1]);
                    acc[uu][vv][co][1] =
                        __builtin_elementwise_fma(xb1, w23, acc[uu][vv][co][1]);
                }
            }
        }
    }
}

__global__ __launch_bounds__(256, 3)
void conv4d_strang(const float* __restrict__ x, const float* __restrict__ w,
                   const float* __restrict__ bias, float* __restrict__ y)
{
    // XCD-chunked decode: chunk=(b, h-half) -> each XCD owns a private 32MB
    // of x. v-tile fastest for L2 halo locality.
    const unsigned orig  = blockIdx.x;       // 0..2047
    const unsigned chunk = orig & 7;         // XCD id under round-robin
    const unsigned rem   = orig >> 3;        // 0..255
    const int b  = chunk >> 1;
    const int ht = chunk & 1;
    const int tu = rem >> 4;                 // 0..15
    const int tv = rem & 15;                 // 0..15
    const int u0 = 2 * tu, v0 = 2 * tv;      // 2x2 (u,v) register tile

    const int wq = threadIdx.x;              // 0..15 -> outputs 2wq, 2wq+1
    const int hy = threadIdx.y;              // 0..15
    const int ho = ht * 16 + hy;             // 0..31
    const int toff = (2 * ho) * kW + 4 * wq;

    v2f acc[2][2][kCout][2];
    #pragma unroll
    for (int co = 0; co < kCout; ++co) {
        const float bb = bias[co];
        #pragma unroll
        for (int uu = 0; uu < 2; ++uu)
            #pragma unroll
            for (int vv = 0; vv < 2; ++vv) {
                acc[uu][vv][co][0] = (v2f){bb, 0.f};
                acc[uu][vv][co][1] = (v2f){bb, 0.f};
            }
    }

    const float* xb = x + (size_t)b * kCin * kCiStride + toff;

    if (tu >= 1 && tu <= 14 && tv >= 1 && tv <= 14) {
        // Interior: all 16 slices valid. Manual depth-2 software pipeline
        // with NAMED buffers (a*/b*): step s+1 loads issue before step s
        // FMAs; live set = exactly 2 load batches, no spill.
        const float* sb = xb + (size_t)((u0 - 1) * kD2 + (v0 - 1)) * kSlice;
        v4f a0[4], a1[4], b0[4], b1[4];
#define SLICE_PTR(E1, E2) (sb + (size_t)((E1) * kD2 + (E2)) * kSlice)
        do_load(SLICE_PTR(0, 0), a0, a1);
        do_load(SLICE_PTR(0, 1), b0, b1);  do_fma<0, 0>(a0, a1, w, acc);
        do_load(SLICE_PTR(0, 2), a0, a1);  do_fma<0, 1>(b0, b1, w, acc);
        do_load(SLICE_PTR(0, 3), b0, b1);  do_fma<0, 2>(a0, a1, w, acc);
        do_load(SLICE_PTR(1, 0), a0, a1);  do_fma<0, 3>(b0, b1, w, acc);
        do_load(SLICE_PTR(1, 1), b0, b1);  do_fma<1, 0>(a0, a1, w, acc);
        do_load(SLICE_PTR(1, 2), a0, a1);  do_fma<1, 1>(b0, b1, w, acc);
        do_load(SLICE_PTR(1, 3), b0, b1);  do_fma<1, 2>(a0, a1, w, acc);
        do_load(SLICE_PTR(2, 0), a0, a1);  do_fma<1, 3>(b0, b1, w, acc);
        do_load(SLICE_PTR(2, 1), b0, b1);  do_fma<2, 0>(a0, a1, w, acc);
        do_load(SLICE_PTR(2, 2), a0, a1);  do_fma<2, 1>(b0, b1, w, acc);
        do_load(SLICE_PTR(2, 3), b0, b1);  do_fma<2, 2>(a0, a1, w, acc);
        do_load(SLICE_PTR(3, 0), a0, a1);  do_fma<2, 3>(b0, b1, w, acc);
        do_load(SLICE_PTR(3, 1), b0, b1);  do_fma<3, 0>(a0, a1, w, acc);
        do_load(SLICE_PTR(3, 2), a0, a1);  do_fma<3, 1>(b0, b1, w, acc);
        do_load(SLICE_PTR(3, 3), b0, b1);  do_fma<3, 2>(a0, a1, w, acc);
        do_fma<3, 3>(b0, b1, w, acc);
#undef SLICE_PTR
    } else {
        // Boundary (23%): wave-uniform skip of out-of-range slices; these
        // blocks do less work, unpipelined is fine.
        v4f a0[4], a1[4];
#define BSTEP(E1, E2)                                                        \
        {                                                                    \
            const int d1 = u0 + (E1) - 1, d2 = v0 + (E2) - 1;                \
            if ((unsigned)d1 < (unsigned)kD1 && (unsigned)d2 < (unsigned)kD2) { \
                do_load(xb + (size_t)(d1 * kD2 + d2) * kSlice, a0, a1);      \
                do_fma<E1, E2>(a0, a1, w, acc);                              \
            }                                                                \
        }
        BSTEP(0, 0) BSTEP(0, 1) BSTEP(0, 2) BSTEP(0, 3)
        BSTEP(1, 0) BSTEP(1, 1) BSTEP(1, 2) BSTEP(1, 3)
        BSTEP(2, 0) BSTEP(2, 1) BSTEP(2, 2) BSTEP(2, 3)
        BSTEP(3, 0) BSTEP(3, 1) BSTEP(3, 2) BSTEP(3, 3)
#undef BSTEP
    }

    #pragma unroll
    for (int co = 0; co < kCout; ++co)
        #pragma unroll
        for (int uu = 0; uu < 2; ++uu)
            #pragma unroll
            for (int vv = 0; vv < 2; ++vv) {
                v2f o;
                o.x = acc[uu][vv][co][0].x + acc[uu][vv][co][0].y;
                o.y = acc[uu][vv][co][1].x + acc[uu][vv][co][1].y;
                float* yp = y
                    + ((((size_t)(b * kCout + co) * kD1 + (u0 + uu)) * kD2 + (v0 + vv)) * kHO + ho) * kWO
                    + 2 * wq;
                *reinterpret_cast<v2f*>(yp) = o;
            }
}

}  // namespace

extern "C" void kernel_launch(void* const* d_in, const int* in_sizes, int n_in,
                              void* d_out, int out_size, void* d_ws, size_t ws_size,
                              hipStream_t stream) {
    const float* x    = (const float*)d_in[0];
    const float* w    = (const float*)d_in[1];
    const float* bias = (const float*)d_in[2];
    float* y          = (float*)d_out;

    dim3 block(16, 16, 1);
    dim3 grid(kB * 2 * 16 * 16, 1, 1);     // 2048 blocks, decoded in-kernel
    hipLaunchKernelGGL(conv4d_strang, grid, block, 0, stream, x, w, bias, y);
}

// Round 9
// 124.189 us; speedup vs baseline: 1.7105x; 1.7105x over previous
//
#include <hip/hip_runtime.h>

namespace {

typedef float v2f __attribute__((ext_vector_type(2)));
typedef float v4f __attribute__((ext_vector_type(4)));

constexpr int kB = 4, kCin = 4, kCout = 4;
constexpr int kD1 = 32, kD2 = 32, kH = 64, kW = 64;
constexpr int kHO = 32, kWO = 32;
constexpr int kSlice = kH * kW;                       // 4096
constexpr size_t kCiStride = (size_t)kD1 * kD2 * kSlice;

__global__ __launch_bounds__(256)
void conv4d_strang(const float* __restrict__ x, const float* __restrict__ w,
                   const float* __restrict__ bias, float* __restrict__ y)
{
    // XCD-chunked decode: chunk=(b, h-half) -> each XCD owns a private 32MB
    // of x. Serpentine tv sweep keeps halo slices L2-hot across transitions.
    const unsigned orig  = blockIdx.x;       // 0..2047
    const unsigned chunk = orig & 7;         // XCD id under round-robin
    const unsigned rem   = orig >> 3;        // 0..255
    const int b  = chunk >> 1;
    const int ht = chunk & 1;
    const int tu = rem >> 4;                 // 0..15
    const int tvr = rem & 15;
    const int tv = (tu & 1) ? (15 - tvr) : tvr;   // serpentine
    const int u0 = 2 * tu, v0 = 2 * tv;      // 2x2 (u,v) register tile

    const int wq = threadIdx.x;              // 0..15 -> outputs 2wq, 2wq+1
    const int hy = threadIdx.y;              // 0..15
    const int ho = ht * 16 + hy;             // 0..31
    const int toff = (2 * ho) * kW + 4 * wq; // per-lane ELEMENT offset

    // acc[uu][vv][co][wo-sub], v2f lanes = (kw-even, kw-odd) partials.
    v2f acc[2][2][kCout][2];
    #pragma unroll
    for (int co = 0; co < kCout; ++co) {
        const float bb = bias[co];
        #pragma unroll
        for (int uu = 0; uu < 2; ++uu)
            #pragma unroll
            for (int vv = 0; vv < 2; ++vv) {
                acc[uu][vv][co][0] = (v2f){bb, 0.f};
                acc[uu][vv][co][1] = (v2f){bb, 0.f};
            }
    }

    // UNIFORM base (no per-lane component): all slice/ci bases stay in
    // SGPRs; the per-lane toff is applied only at the dereference, so the
    // backend emits global_load_dwordx4 v, v_toff, s[base] (+imm for +kW).
    const float* xu = x + (size_t)(b * kCin) * kCiStride;

    #pragma unroll
    for (int e1 = 0; e1 < 4; ++e1) {
        const int d1 = u0 + e1 - 1;
        if ((unsigned)d1 >= (unsigned)kD1) continue;      // wave-uniform
        #pragma unroll
        for (int e2 = 0; e2 < 4; ++e2) {
            const int d2 = v0 + e2 - 1;
            if ((unsigned)d2 >= (unsigned)kD2) continue;  // wave-uniform
            const float* su = xu + (size_t)(d1 * kD2 + d2) * kSlice;  // uniform
            #pragma unroll
            for (int ci = 0; ci < kCin; ++ci) {
                const float* sc = su + (size_t)ci * kCiStride;        // uniform
                const v4f r0 = *reinterpret_cast<const v4f*>(sc + toff);
                const v4f r1 = *reinterpret_cast<const v4f*>(sc + toff + kW);
                const v2f xa0 = r0.xy, xa1 = r0.zw;
                const v2f xb0 = r1.xy, xb1 = r1.zw;
                #pragma unroll
                for (int uu = 0; uu < 2; ++uu) {
                    const int ku = e1 - uu;
                    if (ku < 0 || ku > 2) continue;       // compile-time
                    #pragma unroll
                    for (int vv = 0; vv < 2; ++vv) {
                        const int kv = e2 - vv;
                        if (kv < 0 || kv > 2) continue;   // compile-time
                        #pragma unroll
                        for (int co = 0; co < kCout; ++co) {
                            const float* wp = w + (((co * kCin + ci) * 3 + ku) * 3 + kv) * 4;
                            const v2f w01 = {wp[0], wp[1]};   // kh=0
                            const v2f w23 = {wp[2], wp[3]};   // kh=1
                            acc[uu][vv][co][0] =
                                __builtin_elementwise_fma(xa0, w01, acc[uu][vv][co][0]);
                            acc[uu][vv][co][0] =
                                __builtin_elementwise_fma(xb0, w23, acc[uu][vv][co][0]);
                            acc[uu][vv][co][1] =
                                __builtin_elementwise_fma(xa1, w01, acc[uu][vv][co][1]);
                            acc[uu][vv][co][1] =
                                __builtin_elementwise_fma(xb1, w23, acc[uu][vv][co][1]);
                        }
                    }
                }
            }
        }
    }

    // Non-temporal stores: y is never re-read by this kernel -> don't evict
    // x from L2/L3 with write-allocate traffic.
    #pragma unroll
    for (int co = 0; co < kCout; ++co)
        #pragma unroll
        for (int uu = 0; uu < 2; ++uu)
            #pragma unroll
            for (int vv = 0; vv < 2; ++vv) {
                v2f o;
                o.x = acc[uu][vv][co][0].x + acc[uu][vv][co][0].y;
                o.y = acc[uu][vv][co][1].x + acc[uu][vv][co][1].y;
                float* yp = y
                    + ((((size_t)(b * kCout + co) * kD1 + (u0 + uu)) * kD2 + (v0 + vv)) * kHO + ho) * kWO
                    + 2 * wq;
                __builtin_nontemporal_store(o, reinterpret_cast<v2f*>(yp));
            }
}

}  // namespace

extern "C" void kernel_launch(void* const* d_in, const int* in_sizes, int n_in,
                              void* d_out, int out_size, void* d_ws, size_t ws_size,
                              hipStream_t stream) {
    const float* x    = (const float*)d_in[0];
    const float* w    = (const float*)d_in[1];
    const float* bias = (const float*)d_in[2];
    float* y          = (float*)d_out;

    dim3 block(16, 16, 1);
    dim3 grid(kB * 2 * 16 * 16, 1, 1);     // 2048 blocks, decoded in-kernel
    hipLaunchKernelGGL(conv4d_strang, grid, block, 0, stream, x, w, bias, y);
}